// Round 1
// baseline (411.074 us; speedup 1.0000x reference)
//
#include <hip/hip_runtime.h>

// FWHT over groups of 128 consecutive fp32 elements, scaled by 1/sqrt(128).
// Thread t holds 4 consecutive elements (float4). 32 lanes = one group of 128.
// Stages h=1,2 in-register; h=4,8,16,32,64 via __shfl_xor masks 1,2,4,8,16
// (never crosses the 32-lane half-wave boundary -> 2 groups per wave64).

__global__ __launch_bounds__(256) void fwht128_kernel(const float* __restrict__ x,
                                                      float* __restrict__ out,
                                                      int n4) {
    int idx = blockIdx.x * blockDim.x + threadIdx.x;
    if (idx >= n4) return;

    const float4* __restrict__ in4 = (const float4*)x;
    float4* __restrict__ out4 = (float4*)out;

    float4 v = in4[idx];

    // Stage h=1: pairs (0,1), (2,3)
    float a0 = v.x + v.y;
    float a1 = v.x - v.y;
    float a2 = v.z + v.w;
    float a3 = v.z - v.w;
    // Stage h=2: pairs (0,2), (1,3)
    float r0 = a0 + a2;
    float r1 = a1 + a3;
    float r2 = a0 - a2;
    float r3 = a1 - a3;

    float r[4] = {r0, r1, r2, r3};

    const int lane = threadIdx.x & 63;

    // Stages h=4..64: cross-lane butterflies within each 32-lane group.
    #pragma unroll
    for (int m = 1; m <= 16; m <<= 1) {
        const bool upper = (lane & m) != 0;
        #pragma unroll
        for (int j = 0; j < 4; ++j) {
            float p = __shfl_xor(r[j], m, 64);
            // lower half: a+b (mine + partner); upper half: a-b (partner - mine)
            r[j] = upper ? (p - r[j]) : (r[j] + p);
        }
    }

    constexpr float SCALE = 0.08838834764831845f; // 1/sqrt(128)
    float4 o;
    o.x = r[0] * SCALE;
    o.y = r[1] * SCALE;
    o.z = r[2] * SCALE;
    o.w = r[3] * SCALE;
    out4[idx] = o;
}

extern "C" void kernel_launch(void* const* d_in, const int* in_sizes, int n_in,
                              void* d_out, int out_size, void* d_ws, size_t ws_size,
                              hipStream_t stream) {
    const float* x = (const float*)d_in[0];
    float* out = (float*)d_out;
    int n = in_sizes[0];          // 4*4096*4096 = 67,108,864 (divisible by 128)
    int n4 = n >> 2;              // float4 count
    const int block = 256;
    int grid = (n4 + block - 1) / block;
    fwht128_kernel<<<grid, block, 0, stream>>>(x, out, n4);
}